// Round 1
// baseline (235.100 us; speedup 1.0000x reference)
//
#include <hip/hip_runtime.h>
#include <hip/hip_fp16.h>
#include <cstdint>
#include <cstddef>

#define NN 100000
#define NE 1600000
#define D 128
#define NBK 782            // ceil(NN / 128) buckets of 128 nodes
#define NBLK_P 200         // partition blocks
#define EPB 8000           // edges per partition block (200*8000 = 1.6M exact)

typedef _Float16 half8 __attribute__((ext_vector_type(8)));
typedef _Float16 half4v __attribute__((ext_vector_type(4)));
typedef float f32x4 __attribute__((ext_vector_type(4)));

// ---------------- workspace layout (bytes) ----------------
// part  : NE u32      @ 0          (6,400,000)   } dead after p4_csr; overlapped by h
// offs  : 200*782 u32 @ 6,400,000  (  625,600)   }
// base  : 783 u32     @ 7,100,000  (    3,132)   }
// h'    : NN*128 f16  @ 0          (25,600,000)  = dinv[row] * (x@W1), written after CSR
// z'    : NN*2 f32    @ 25,600,000 (   800,000)  = dinv[row] * (relu(agg+b1)@W2)
// dinv  : NN f32      @ 26,400,000 (   400,000)
// rp    : NN+1 u32    @ 26,800,000 (   400,004)
// col   : NE u32      @ 27,200,016 ( 6,400,000)
// Wt    : 128*128 f16 @ 33,600,016 (    32,768)  -> total 33,632,784

// P1: per-block LDS histogram over dst buckets (int4 edge loads, no global atomics).
// Blocks 0..63 additionally emit Wt[n][k] = fp16 W1[k][n] (fused wt_k).
__launch_bounds__(256)
__global__ void p1_count_k(const int* __restrict__ ei, unsigned* __restrict__ offs,
                           const float* __restrict__ W, _Float16* __restrict__ Wt) {
    __shared__ unsigned hist[NBK];
    int tid = threadIdx.x, b = blockIdx.x;
    for (int k = tid; k < NBK; k += 256) hist[k] = 0u;
    __syncthreads();
    int e0 = b * EPB;
    for (int i = tid * 4; i < EPB; i += 1024) {
        int4 d4 = *(const int4*)(ei + NE + e0 + i);
        atomicAdd(&hist[d4.x >> 7], 1u);
        atomicAdd(&hist[d4.y >> 7], 1u);
        atomicAdd(&hist[d4.z >> 7], 1u);
        atomicAdd(&hist[d4.w >> 7], 1u);
    }
    __syncthreads();
    for (int k = tid; k < NBK; k += 256) offs[(size_t)b * NBK + k] = hist[k];

    if (b < 64) {  // fused Wt transpose+cast (16384 elems over 64 blocks)
        int idx = b * 256 + tid;
        int n = idx >> 7, k = idx & 127;
        Wt[idx] = (_Float16)W[k * 128 + n];
    }
}

// P2a: block per bucket; parallel loads of the 200 per-block counts + LDS scan.
__launch_bounds__(256)
__global__ void p2a_k(unsigned* __restrict__ offs, unsigned* __restrict__ base) {
    __shared__ unsigned sh[256];
    int t = threadIdx.x, k = blockIdx.x;
    unsigned v = (t < NBLK_P) ? offs[(size_t)t * NBK + k] : 0u;
    sh[t] = v;
    __syncthreads();
    for (int off = 1; off < 256; off <<= 1) {
        unsigned u = (t >= off) ? sh[t - off] : 0u;
        __syncthreads();
        sh[t] += u;
        __syncthreads();
    }
    if (t < NBLK_P) offs[(size_t)t * NBK + k] = sh[t] - v;  // exclusive
    if (t == 255) base[k] = sh[255];                         // bucket total
}

// P2b: exclusive scan of bucket totals; base[NBK] = NE.
__global__ void p2b_k(unsigned* __restrict__ base) {
    __shared__ unsigned sh[1024];
    int t = threadIdx.x;
    unsigned v = (t < NBK) ? base[t] : 0u;
    sh[t] = v;
    __syncthreads();
    for (int off = 1; off < 1024; off <<= 1) {
        unsigned u = (t >= off) ? sh[t - off] : 0u;
        __syncthreads();
        sh[t] += u;
        __syncthreads();
    }
    if (t < NBK) base[t] = sh[t] - v;
    if (t == NBK) base[NBK] = sh[NBK - 1];
}

// P3: scatter packed edges into bucket-partitioned order via LDS running counters.
__launch_bounds__(256)
__global__ void p3_scatter_k(const int* __restrict__ ei, const unsigned* __restrict__ offs,
                             const unsigned* __restrict__ base, unsigned* __restrict__ part) {
    __shared__ unsigned lcnt[NBK];
    int tid = threadIdx.x, b = blockIdx.x;
    for (int k = tid; k < NBK; k += 256) lcnt[k] = base[k] + offs[(size_t)b * NBK + k];
    __syncthreads();
    int e0 = b * EPB;
    for (int i = tid * 4; i < EPB; i += 1024) {
        int4 s4 = *(const int4*)(ei + e0 + i);
        int4 d4 = *(const int4*)(ei + NE + e0 + i);
        unsigned p;
        p = atomicAdd(&lcnt[d4.x >> 7], 1u); part[p] = (unsigned)s4.x | ((unsigned)(d4.x & 127) << 20);
        p = atomicAdd(&lcnt[d4.y >> 7], 1u); part[p] = (unsigned)s4.y | ((unsigned)(d4.y & 127) << 20);
        p = atomicAdd(&lcnt[d4.z >> 7], 1u); part[p] = (unsigned)s4.z | ((unsigned)(d4.z & 127) << 20);
        p = atomicAdd(&lcnt[d4.w >> 7], 1u); part[p] = (unsigned)s4.w | ((unsigned)(d4.w & 127) << 20);
    }
}

// P4: one block per bucket. Count per node in LDS, scan, emit rp/dinv, regroup col.
__launch_bounds__(256)
__global__ void p4_csr_k(const unsigned* __restrict__ part, const unsigned* __restrict__ base,
                         unsigned* __restrict__ rp, float* __restrict__ dinv,
                         unsigned* __restrict__ col) {
    __shared__ unsigned c[128], p[128], run[128];
    int tid = threadIdx.x, k = blockIdx.x;
    int n0 = k << 7;
    int nodes = (NN - n0 < 128) ? (NN - n0) : 128;
    unsigned e0 = base[k], e1 = base[k + 1];

    if (tid < 128) c[tid] = 0u;
    __syncthreads();
    for (unsigned e = e0 + tid; e < e1; e += 256)
        atomicAdd(&c[(part[e] >> 20) & 127], 1u);
    __syncthreads();

    unsigned myc = (tid < 128) ? c[tid] : 0u;
    if (tid < 128) p[tid] = myc;
    __syncthreads();
    for (int off = 1; off < 128; off <<= 1) {
        unsigned u = 0;
        if (tid < 128 && tid >= off) u = p[tid - off];
        __syncthreads();
        if (tid < 128) p[tid] += u;
        __syncthreads();
    }
    if (tid < 128) {
        unsigned excl = p[tid] - myc;
        run[tid] = excl;
        if (tid < nodes) {
            rp[n0 + tid] = e0 + excl;
            dinv[n0 + tid] = rsqrtf((float)(myc + 1u));
        }
    }
    if (k == 0 && tid == 0) rp[NN] = NE;
    __syncthreads();

    for (unsigned e = e0 + tid; e < e1; e += 256) {
        unsigned v = part[e];
        unsigned dlo = (v >> 20) & 127;
        unsigned pos = e0 + atomicAdd(&run[dlo], 1u);
        col[pos] = v & 0xFFFFFu;
    }
}

// h' = dinv ⊙ (x @ W1), fp16 out, MFMA 16x16x32 f16. 128 rows/block, 4 waves;
// wave w covers rows w*32..w*32+31 (2 row-tiles) × all 8 col-tiles -> B-frag
// reused across 2 MFMAs. x staged in K-halves of 64 so LDS = 34.8K (wt) +
// 18.4K (xs) = 52K -> 3 blocks/CU; 782 blocks ≈ one co-resident round.
// Verified layouts: A[m=lane&15][k=(lane>>4)*8+j], B[k][n=lane&15],
//                   C/D col=lane&15 row=(lane>>4)*4+reg.
__launch_bounds__(256)
__global__ void gemm1_k(const float* __restrict__ x, const _Float16* __restrict__ Wt,
                        const float* __restrict__ dinv, _Float16* __restrict__ h) {
    __shared__ _Float16 wt[128 * 136];  // B: wt[n][k]; reused as epilogue buffer
    __shared__ _Float16 xs[128 * 72];   // A: xs[row][k within 64-half]
    int tid = threadIdx.x;
    int rb = blockIdx.x * 128;
    int w = tid >> 6, lane = tid & 63;
    int m = lane & 15, q4 = lane >> 4;

    // stage Wt: 2048 half8 chunks, coalesced global, conflict-free LDS
#pragma unroll
    for (int q = 0; q < 8; q++) {
        int idx = q * 256 + tid;
        int n = idx >> 4, k8 = (idx & 15) * 8;
        *(half8*)(&wt[n * 136 + k8]) = *(const half8*)(Wt + n * 128 + k8);
    }

    f32x4 acc[2][8];
#pragma unroll
    for (int rt = 0; rt < 2; rt++)
#pragma unroll
        for (int nt = 0; nt < 8; nt++) acc[rt][nt] = (f32x4){0.f, 0.f, 0.f, 0.f};

    for (int ks = 0; ks <= 64; ks += 64) {
        if (ks) __syncthreads();  // previous xs fully consumed
        // stage x rows [rb, rb+128) cols [ks, ks+64), fp32 -> fp16
#pragma unroll
        for (int q = 0; q < 8; q++) {
            int idx = q * 256 + tid;        // 0..2047
            int row = idx >> 4;
            int c4 = (idx & 15) * 4;
            int gr = rb + row;
            float4 v = (gr < NN) ? *(const float4*)(x + (size_t)gr * 128 + ks + c4)
                                 : make_float4(0, 0, 0, 0);
            half4v hv = { (_Float16)v.x, (_Float16)v.y, (_Float16)v.z, (_Float16)v.w };
            *(half4v*)(&xs[row * 72 + c4]) = hv;
        }
        __syncthreads();

#pragma unroll
        for (int kc = 0; kc < 2; kc++) {
            half8 a0 = *(const half8*)(&xs[(w * 32 + m) * 72 + kc * 32 + q4 * 8]);
            half8 a1 = *(const half8*)(&xs[(w * 32 + 16 + m) * 72 + kc * 32 + q4 * 8]);
#pragma unroll
            for (int nt = 0; nt < 8; nt++) {
                half8 bf = *(const half8*)(&wt[(nt * 16 + m) * 136 + ks + kc * 32 + q4 * 8]);
                acc[0][nt] = __builtin_amdgcn_mfma_f32_16x16x32_f16(a0, bf, acc[0][nt], 0, 0, 0);
                acc[1][nt] = __builtin_amdgcn_mfma_f32_16x16x32_f16(a1, bf, acc[1][nt], 0, 0, 0);
            }
        }
    }

    // epilogue: scale by dinv[row], fp16, stage in wt (dead), coalesced store
    float dv[2][4];
#pragma unroll
    for (int rt = 0; rt < 2; rt++)
#pragma unroll
        for (int r = 0; r < 4; r++) {
            int ri = rb + w * 32 + rt * 16 + q4 * 4 + r;
            dv[rt][r] = (ri < NN) ? dinv[ri] : 0.f;
        }
    __syncthreads();  // all wt reads done
#pragma unroll
    for (int rt = 0; rt < 2; rt++)
#pragma unroll
        for (int nt = 0; nt < 8; nt++)
#pragma unroll
            for (int r = 0; r < 4; r++)
                wt[(w * 32 + rt * 16 + q4 * 4 + r) * 136 + nt * 16 + m] =
                    (_Float16)(acc[rt][nt][r] * dv[rt][r]);
    __syncthreads();
#pragma unroll
    for (int q = 0; q < 8; q++) {
        int idx = q * 256 + tid;
        int row = idx >> 4;
        int c8 = (idx & 15) * 8;
        int gr = rb + row;
        if (gr < NN)
            *(half8*)(h + (size_t)gr * 128 + c8) = *(const half8*)(&wt[row * 136 + c8]);
    }
}

// Layer-1 aggregation of prescaled h' + bias/ReLU + 128x2 W2 projection.
// One wave per node. Lane split: g = lane>>4 (edge slot), c = lane&15 (16B row
// chunk). Each VMEM instruction gathers 4 rows (dwordx4/lane, 1 KB/wave) -> 4x
// payload per issued load vs the old dword GATHER, and the degree tail is one
// branch-free masked round instead of serialized 4-/1-deep loops (masked slots
// clamp to row 0, L1-hot, zeroed via fma-mask). fp32 accumulate, cross-group
// combine via shfl_xor(16|32), then per-chunk bias/ReLU/W2 and width-16 reduce.
__launch_bounds__(256)
__global__ void agg1_k(const _Float16* __restrict__ h, const unsigned* __restrict__ rp,
                       const unsigned* __restrict__ col, const float* __restrict__ dinv,
                       const float* __restrict__ b1, const float* __restrict__ W2,
                       float* __restrict__ z) {
    int i = (blockIdx.x * 256 + threadIdx.x) >> 6;
    int lane = threadIdx.x & 63;
    if (i >= NN) return;
    int g = lane >> 4;   // edge slot within quad
    int c = lane & 15;   // 16B chunk within row
    const _Float16* hc = h + (size_t)c * 8;

    float acc[8];
    {   // self term h'[i], counted once (group 0 only; other groups zeroed)
        half8 sv = *(const half8*)(hc + (size_t)i * 128);
        float mm = (g == 0) ? 1.f : 0.f;
#pragma unroll
        for (int j = 0; j < 8; j++) acc[j] = mm * (float)sv[j];
    }

    unsigned p0 = __builtin_amdgcn_readfirstlane(rp[i]);
    unsigned p1 = __builtin_amdgcn_readfirstlane(rp[i + 1]);
    for (unsigned e = p0; e < p1; e += 16) {
        half8 v[4];
        float mm[4];
#pragma unroll
        for (int q = 0; q < 4; q++) {
            unsigned idx = e + q * 4u + (unsigned)g;
            bool lt = idx < p1;
            mm[q] = lt ? 1.f : 0.f;
            unsigned s = lt ? col[idx] : 0u;   // masked slots read row 0 (hot)
            v[q] = *(const half8*)(hc + (size_t)s * 128);
        }
#pragma unroll
        for (int q = 0; q < 4; q++)
#pragma unroll
            for (int j = 0; j < 8; j++)
                acc[j] = fmaf(mm[q], (float)v[q][j], acc[j]);
    }

    // combine the 4 edge-slot partials: groups hold same dims, different edges
#pragma unroll
    for (int j = 0; j < 8; j++) {
        acc[j] += __shfl_xor(acc[j], 16);
        acc[j] += __shfl_xor(acc[j], 32);
    }

    float di = dinv[i];
    const float4* b4 = (const float4*)b1;
    float4 ba = b4[c * 2], bb = b4[c * 2 + 1];
    float hh[8];
    hh[0] = fmaxf(fmaf(acc[0], di, ba.x), 0.f);
    hh[1] = fmaxf(fmaf(acc[1], di, ba.y), 0.f);
    hh[2] = fmaxf(fmaf(acc[2], di, ba.z), 0.f);
    hh[3] = fmaxf(fmaf(acc[3], di, ba.w), 0.f);
    hh[4] = fmaxf(fmaf(acc[4], di, bb.x), 0.f);
    hh[5] = fmaxf(fmaf(acc[5], di, bb.y), 0.f);
    hh[6] = fmaxf(fmaf(acc[6], di, bb.z), 0.f);
    hh[7] = fmaxf(fmaf(acc[7], di, bb.w), 0.f);

    const float4* w4 = (const float4*)W2;   // W2[d][0..1] row-major
    float4 w0 = w4[c * 4], w1 = w4[c * 4 + 1], w2v = w4[c * 4 + 2], w3 = w4[c * 4 + 3];
    float pz0 = hh[0] * w0.x + hh[1] * w0.z + hh[2] * w1.x + hh[3] * w1.z
              + hh[4] * w2v.x + hh[5] * w2v.z + hh[6] * w3.x + hh[7] * w3.z;
    float pz1 = hh[0] * w0.y + hh[1] * w0.w + hh[2] * w1.y + hh[3] * w1.w
              + hh[4] * w2v.y + hh[5] * w2v.w + hh[6] * w3.y + hh[7] * w3.w;
#pragma unroll
    for (int off = 8; off > 0; off >>= 1) {
        pz0 += __shfl_xor(pz0, off);
        pz1 += __shfl_xor(pz1, off);
    }
    if (lane == 0) {
        float2* zp = (float2*)(z + (size_t)i * 2);
        *zp = make_float2(pz0 * di, pz1 * di);  // prescale for layer-2 aggregation
    }
}

// Layer-2 aggregation over prescaled z'. 16 lanes per node (avg degree 16):
// 4 nodes/wave, width-16 shuffle reduce. out[i] = (Σ z'[s] + z'[i])*dinv[i] + b2.
__launch_bounds__(256)
__global__ void agg2_k(const float* __restrict__ z, const unsigned* __restrict__ rp,
                       const unsigned* __restrict__ col, const float* __restrict__ dinv,
                       const float* __restrict__ b2, float* __restrict__ out) {
    int i = (blockIdx.x * 256 + threadIdx.x) >> 4;
    int sl = threadIdx.x & 15;
    if (i >= NN) return;

    unsigned p0 = rp[i], p1 = rp[i + 1];
    float a0 = 0.f, a1 = 0.f;
    for (unsigned e = p0 + sl; e < p1; e += 16) {
        unsigned s = col[e];
        float2 v = ((const float2*)z)[s];
        a0 += v.x;
        a1 += v.y;
    }
#pragma unroll
    for (int off = 8; off > 0; off >>= 1) {
        a0 += __shfl_down(a0, off, 16);
        a1 += __shfl_down(a1, off, 16);
    }
    if (sl == 0) {
        float di = dinv[i];
        float2 zi = ((const float2*)z)[i];
        out[(size_t)i * 2]     = (a0 + zi.x) * di + b2[0];
        out[(size_t)i * 2 + 1] = (a1 + zi.y) * di + b2[1];
    }
}

extern "C" void kernel_launch(void* const* d_in, const int* in_sizes, int n_in,
                              void* d_out, int out_size, void* d_ws, size_t ws_size,
                              hipStream_t stream) {
    const float* x  = (const float*)d_in[0];
    const int*   ei = (const int*)d_in[1];
    const float* W1 = (const float*)d_in[2];
    const float* b1 = (const float*)d_in[3];
    const float* W2 = (const float*)d_in[4];
    const float* b2 = (const float*)d_in[5];
    float* out = (float*)d_out;

    char* ws = (char*)d_ws;
    unsigned* part = (unsigned*)(ws);               // overlaps h, dead before gemm1
    unsigned* offs = (unsigned*)(ws + 6400000);     // overlaps h
    unsigned* base = (unsigned*)(ws + 7100000);     // overlaps h
    _Float16* h    = (_Float16*)(ws);
    float*    z    = (float*)(ws + 25600000);
    float*    dinv = (float*)(ws + 26400000);
    unsigned* rp   = (unsigned*)(ws + 26800000);
    unsigned* col  = (unsigned*)(ws + 27200016);
    _Float16* Wt   = (_Float16*)(ws + 33600016);

    p1_count_k<<<NBLK_P, 256, 0, stream>>>(ei, offs, W1, Wt);
    p2a_k<<<NBK, 256, 0, stream>>>(offs, base);
    p2b_k<<<1, 1024, 0, stream>>>(base);
    p3_scatter_k<<<NBLK_P, 256, 0, stream>>>(ei, offs, base, part);
    p4_csr_k<<<NBK, 256, 0, stream>>>(part, base, rp, dinv, col);

    gemm1_k<<<(NN + 127) / 128, 256, 0, stream>>>(x, Wt, dinv, h);
    agg1_k<<<(NN + 3) / 4, 256, 0, stream>>>(h, rp, col, dinv, b1, W2, z);
    agg2_k<<<(NN * 16 + 255) / 256, 256, 0, stream>>>(z, rp, col, dinv, b2, out);
}

// Round 2
// 224.394 us; speedup vs baseline: 1.0477x; 1.0477x over previous
//
#include <hip/hip_runtime.h>
#include <hip/hip_fp16.h>
#include <cstdint>
#include <cstddef>

#define NN 100000
#define NE 1600000
#define D 128
#define NBK 782            // ceil(NN / 128) buckets of 128 nodes
#define NBLK_P 200         // partition blocks
#define EPB 8000           // edges per partition block (200*8000 = 1.6M exact)

typedef _Float16 half8 __attribute__((ext_vector_type(8)));
typedef _Float16 half4v __attribute__((ext_vector_type(4)));
typedef float f32x4 __attribute__((ext_vector_type(4)));

// ---------------- workspace layout (bytes) ----------------
// part  : NE u32      @ 0          (6,400,000)   } dead after p4_csr; overlapped by h
// offs  : 200*782 u32 @ 6,400,000  (  625,600)   }
// base  : 783 u32     @ 7,100,000  (    3,132)   }
// h'    : NN*128 f16  @ 0          (25,600,000)  = dinv[row] * (x@W1), written after CSR
// z'    : NN*2 f32    @ 25,600,000 (   800,000)  = dinv[row] * (relu(agg+b1)@W2)
// dinv  : NN f32      @ 26,400,000 (   400,000)
// rp    : NN+1 u32    @ 26,800,000 (   400,004)
// col   : NE u32      @ 27,200,016 ( 6,400,000)
// Wt    : 128*128 f16 @ 33,600,016 (    32,768)  -> total 33,632,784
// NOTE: agg1's col-window load may read up to col[NE+63] -> lands in Wt region
// (allocated, values unused — masked by uniform (k<deg) selects).

// P1: per-block LDS histogram over dst buckets (int4 edge loads, no global atomics).
// Blocks 0..63 additionally emit Wt[n][k] = fp16 W1[k][n] (fused wt_k).
__launch_bounds__(256)
__global__ void p1_count_k(const int* __restrict__ ei, unsigned* __restrict__ offs,
                           const float* __restrict__ W, _Float16* __restrict__ Wt) {
    __shared__ unsigned hist[NBK];
    int tid = threadIdx.x, b = blockIdx.x;
    for (int k = tid; k < NBK; k += 256) hist[k] = 0u;
    __syncthreads();
    int e0 = b * EPB;
    for (int i = tid * 4; i < EPB; i += 1024) {
        int4 d4 = *(const int4*)(ei + NE + e0 + i);
        atomicAdd(&hist[d4.x >> 7], 1u);
        atomicAdd(&hist[d4.y >> 7], 1u);
        atomicAdd(&hist[d4.z >> 7], 1u);
        atomicAdd(&hist[d4.w >> 7], 1u);
    }
    __syncthreads();
    for (int k = tid; k < NBK; k += 256) offs[(size_t)b * NBK + k] = hist[k];

    if (b < 64) {  // fused Wt transpose+cast (16384 elems over 64 blocks)
        int idx = b * 256 + tid;
        int n = idx >> 7, k = idx & 127;
        Wt[idx] = (_Float16)W[k * 128 + n];
    }
}

// P2a: block per bucket; parallel loads of the 200 per-block counts + LDS scan.
__launch_bounds__(256)
__global__ void p2a_k(unsigned* __restrict__ offs, unsigned* __restrict__ base) {
    __shared__ unsigned sh[256];
    int t = threadIdx.x, k = blockIdx.x;
    unsigned v = (t < NBLK_P) ? offs[(size_t)t * NBK + k] : 0u;
    sh[t] = v;
    __syncthreads();
    for (int off = 1; off < 256; off <<= 1) {
        unsigned u = (t >= off) ? sh[t - off] : 0u;
        __syncthreads();
        sh[t] += u;
        __syncthreads();
    }
    if (t < NBLK_P) offs[(size_t)t * NBK + k] = sh[t] - v;  // exclusive
    if (t == 255) base[k] = sh[255];                         // bucket total
}

// P2b: exclusive scan of bucket totals; base[NBK] = NE.
__global__ void p2b_k(unsigned* __restrict__ base) {
    __shared__ unsigned sh[1024];
    int t = threadIdx.x;
    unsigned v = (t < NBK) ? base[t] : 0u;
    sh[t] = v;
    __syncthreads();
    for (int off = 1; off < 1024; off <<= 1) {
        unsigned u = (t >= off) ? sh[t - off] : 0u;
        __syncthreads();
        sh[t] += u;
        __syncthreads();
    }
    if (t < NBK) base[t] = sh[t] - v;
    if (t == NBK) base[NBK] = sh[NBK - 1];
}

// P3: scatter packed edges into bucket-partitioned order via LDS running counters.
__launch_bounds__(256)
__global__ void p3_scatter_k(const int* __restrict__ ei, const unsigned* __restrict__ offs,
                             const unsigned* __restrict__ base, unsigned* __restrict__ part) {
    __shared__ unsigned lcnt[NBK];
    int tid = threadIdx.x, b = blockIdx.x;
    for (int k = tid; k < NBK; k += 256) lcnt[k] = base[k] + offs[(size_t)b * NBK + k];
    __syncthreads();
    int e0 = b * EPB;
    for (int i = tid * 4; i < EPB; i += 1024) {
        int4 s4 = *(const int4*)(ei + e0 + i);
        int4 d4 = *(const int4*)(ei + NE + e0 + i);
        unsigned p;
        p = atomicAdd(&lcnt[d4.x >> 7], 1u); part[p] = (unsigned)s4.x | ((unsigned)(d4.x & 127) << 20);
        p = atomicAdd(&lcnt[d4.y >> 7], 1u); part[p] = (unsigned)s4.y | ((unsigned)(d4.y & 127) << 20);
        p = atomicAdd(&lcnt[d4.z >> 7], 1u); part[p] = (unsigned)s4.z | ((unsigned)(d4.z & 127) << 20);
        p = atomicAdd(&lcnt[d4.w >> 7], 1u); part[p] = (unsigned)s4.w | ((unsigned)(d4.w & 127) << 20);
    }
}

// P4: one block per bucket. Count per node in LDS, scan, emit rp/dinv, regroup col.
__launch_bounds__(256)
__global__ void p4_csr_k(const unsigned* __restrict__ part, const unsigned* __restrict__ base,
                         unsigned* __restrict__ rp, float* __restrict__ dinv,
                         unsigned* __restrict__ col) {
    __shared__ unsigned c[128], p[128], run[128];
    int tid = threadIdx.x, k = blockIdx.x;
    int n0 = k << 7;
    int nodes = (NN - n0 < 128) ? (NN - n0) : 128;
    unsigned e0 = base[k], e1 = base[k + 1];

    if (tid < 128) c[tid] = 0u;
    __syncthreads();
    for (unsigned e = e0 + tid; e < e1; e += 256)
        atomicAdd(&c[(part[e] >> 20) & 127], 1u);
    __syncthreads();

    unsigned myc = (tid < 128) ? c[tid] : 0u;
    if (tid < 128) p[tid] = myc;
    __syncthreads();
    for (int off = 1; off < 128; off <<= 1) {
        unsigned u = 0;
        if (tid < 128 && tid >= off) u = p[tid - off];
        __syncthreads();
        if (tid < 128) p[tid] += u;
        __syncthreads();
    }
    if (tid < 128) {
        unsigned excl = p[tid] - myc;
        run[tid] = excl;
        if (tid < nodes) {
            rp[n0 + tid] = e0 + excl;
            dinv[n0 + tid] = rsqrtf((float)(myc + 1u));
        }
    }
    if (k == 0 && tid == 0) rp[NN] = NE;
    __syncthreads();

    for (unsigned e = e0 + tid; e < e1; e += 256) {
        unsigned v = part[e];
        unsigned dlo = (v >> 20) & 127;
        unsigned pos = e0 + atomicAdd(&run[dlo], 1u);
        col[pos] = v & 0xFFFFFu;
    }
}

// h' = dinv ⊙ (x @ W1), fp16 out, MFMA 16x16x32 f16. 128 rows/block, 4 waves;
// wave w covers rows w*32..w*32+31 (2 row-tiles) × all 8 col-tiles -> B-frag
// reused across 2 MFMAs. x staged in K-halves of 64 so LDS = 34.8K (wt) +
// 18.4K (xs) = 52K -> 3 blocks/CU; 782 blocks ≈ one co-resident round.
// Verified layouts: A[m=lane&15][k=(lane>>4)*8+j], B[k][n=lane&15],
//                   C/D col=lane&15 row=(lane>>4)*4+reg.
__launch_bounds__(256)
__global__ void gemm1_k(const float* __restrict__ x, const _Float16* __restrict__ Wt,
                        const float* __restrict__ dinv, _Float16* __restrict__ h) {
    __shared__ _Float16 wt[128 * 136];  // B: wt[n][k]; reused as epilogue buffer
    __shared__ _Float16 xs[128 * 72];   // A: xs[row][k within 64-half]
    int tid = threadIdx.x;
    int rb = blockIdx.x * 128;
    int w = tid >> 6, lane = tid & 63;
    int m = lane & 15, q4 = lane >> 4;

    // stage Wt: 2048 half8 chunks, coalesced global, conflict-free LDS
#pragma unroll
    for (int q = 0; q < 8; q++) {
        int idx = q * 256 + tid;
        int n = idx >> 4, k8 = (idx & 15) * 8;
        *(half8*)(&wt[n * 136 + k8]) = *(const half8*)(Wt + n * 128 + k8);
    }

    f32x4 acc[2][8];
#pragma unroll
    for (int rt = 0; rt < 2; rt++)
#pragma unroll
        for (int nt = 0; nt < 8; nt++) acc[rt][nt] = (f32x4){0.f, 0.f, 0.f, 0.f};

    for (int ks = 0; ks <= 64; ks += 64) {
        if (ks) __syncthreads();  // previous xs fully consumed
        // stage x rows [rb, rb+128) cols [ks, ks+64), fp32 -> fp16
#pragma unroll
        for (int q = 0; q < 8; q++) {
            int idx = q * 256 + tid;        // 0..2047
            int row = idx >> 4;
            int c4 = (idx & 15) * 4;
            int gr = rb + row;
            float4 v = (gr < NN) ? *(const float4*)(x + (size_t)gr * 128 + ks + c4)
                                 : make_float4(0, 0, 0, 0);
            half4v hv = { (_Float16)v.x, (_Float16)v.y, (_Float16)v.z, (_Float16)v.w };
            *(half4v*)(&xs[row * 72 + c4]) = hv;
        }
        __syncthreads();

#pragma unroll
        for (int kc = 0; kc < 2; kc++) {
            half8 a0 = *(const half8*)(&xs[(w * 32 + m) * 72 + kc * 32 + q4 * 8]);
            half8 a1 = *(const half8*)(&xs[(w * 32 + 16 + m) * 72 + kc * 32 + q4 * 8]);
#pragma unroll
            for (int nt = 0; nt < 8; nt++) {
                half8 bf = *(const half8*)(&wt[(nt * 16 + m) * 136 + ks + kc * 32 + q4 * 8]);
                acc[0][nt] = __builtin_amdgcn_mfma_f32_16x16x32_f16(a0, bf, acc[0][nt], 0, 0, 0);
                acc[1][nt] = __builtin_amdgcn_mfma_f32_16x16x32_f16(a1, bf, acc[1][nt], 0, 0, 0);
            }
        }
    }

    // epilogue: scale by dinv[row], fp16, stage in wt (dead), coalesced store
    float dv[2][4];
#pragma unroll
    for (int rt = 0; rt < 2; rt++)
#pragma unroll
        for (int r = 0; r < 4; r++) {
            int ri = rb + w * 32 + rt * 16 + q4 * 4 + r;
            dv[rt][r] = (ri < NN) ? dinv[ri] : 0.f;
        }
    __syncthreads();  // all wt reads done
#pragma unroll
    for (int rt = 0; rt < 2; rt++)
#pragma unroll
        for (int nt = 0; nt < 8; nt++)
#pragma unroll
            for (int r = 0; r < 4; r++)
                wt[(w * 32 + rt * 16 + q4 * 4 + r) * 136 + nt * 16 + m] =
                    (_Float16)(acc[rt][nt][r] * dv[rt][r]);
    __syncthreads();
#pragma unroll
    for (int q = 0; q < 8; q++) {
        int idx = q * 256 + tid;
        int row = idx >> 4;
        int c8 = (idx & 15) * 8;
        int gr = rb + row;
        if (gr < NN)
            *(half8*)(h + (size_t)gr * 128 + c8) = *(const half8*)(&wt[row * 136 + c8]);
    }
}

// Layer-1 aggregation of prescaled h' + bias/ReLU + 128x2 W2 projection.
// One wave per node; lane holds half2 (row chunk of 4B, 64 lanes = 256B row).
// Col window loaded ONCE per node (col[p0+lane], 1 instr for up to 64 ids);
// row ids via readlane -> SGPR-based gather addresses (zero per-lane addr math).
// No degree tails: always full 16-gather rounds; padding slots gather row i
// (L1-hot) via wave-uniform s_cselect, over-count corrected exactly by the
// self-term coefficient f = 1 + deg - 16*ceil(deg/16). fp32 accumulate.
__launch_bounds__(256)
__global__ void agg1_k(const _Float16* __restrict__ h, const unsigned* __restrict__ rp,
                       const unsigned* __restrict__ col, const float* __restrict__ dinv,
                       const float* __restrict__ b1, const float* __restrict__ W2,
                       float* __restrict__ z) {
    int i = (blockIdx.x * 256 + threadIdx.x) >> 6;
    int lane = threadIdx.x & 63;
    if (i >= NN) return;
    unsigned si = __builtin_amdgcn_readfirstlane((unsigned)i);  // force SGPR

    const __half2* hb = (const __half2*)h;
    unsigned p0 = __builtin_amdgcn_readfirstlane(rp[si]);
    unsigned p1 = __builtin_amdgcn_readfirstlane(rp[si + 1]);
    int deg = (int)(p1 - p0);

    // col window: one per-lane load covers up to 64 edge ids. May read past p1
    // (stays inside allocated workspace); unused lanes masked by (k<degc).
    unsigned cv = col[p0 + (unsigned)lane];

    int degc = deg > 64 ? 64 : deg;
    int R = (degc + 15) >> 4;                 // full 16-rounds incl. padding
    float2 sv = __half22float2(hb[(size_t)si * 64u + lane]);
    float f = (float)(1 + degc - 16 * R);     // corrects padding reads of row si
    float ax = f * sv.x, ay = f * sv.y;

#define ROUND16(r)                                                           \
    {                                                                        \
        float2 vv[16];                                                       \
        _Pragma("unroll")                                                    \
        for (int t = 0; t < 16; t++) {                                       \
            int k = (r) * 16 + t;                                            \
            unsigned s = (k < degc) ? __builtin_amdgcn_readlane(cv, k) : si; \
            vv[t] = __half22float2(hb[(size_t)s * 64u + lane]);              \
        }                                                                    \
        ax += ((vv[0].x + vv[1].x) + (vv[2].x + vv[3].x))                    \
            + ((vv[4].x + vv[5].x) + (vv[6].x + vv[7].x))                    \
            + ((vv[8].x + vv[9].x) + (vv[10].x + vv[11].x))                  \
            + ((vv[12].x + vv[13].x) + (vv[14].x + vv[15].x));               \
        ay += ((vv[0].y + vv[1].y) + (vv[2].y + vv[3].y))                    \
            + ((vv[4].y + vv[5].y) + (vv[6].y + vv[7].y))                    \
            + ((vv[8].y + vv[9].y) + (vv[10].y + vv[11].y))                  \
            + ((vv[12].y + vv[13].y) + (vv[14].y + vv[15].y));               \
    }

    if (degc > 0)  ROUND16(0)
    if (degc > 16) ROUND16(1)
    if (degc > 32) ROUND16(2)
    if (degc > 48) ROUND16(3)
#undef ROUND16

    // deg > 64 remainder (Poisson(16): essentially never taken)
    for (unsigned e = p0 + 64; e < p1; ++e) {
        unsigned s_ = __builtin_amdgcn_readfirstlane(col[e]);
        float2 v = __half22float2(hb[(size_t)s_ * 64u + lane]);
        ax += v.x;
        ay += v.y;
    }

    float di = dinv[si];
    ax *= di;
    ay *= di;

    float2 bv = ((const float2*)b1)[lane];
    float h0 = fmaxf(ax + bv.x, 0.f);
    float h1 = fmaxf(ay + bv.y, 0.f);

    float4 w = ((const float4*)W2)[lane];
    float pz0 = fmaf(h0, w.x, h1 * w.z);
    float pz1 = fmaf(h0, w.y, h1 * w.w);
#pragma unroll
    for (int off = 32; off > 0; off >>= 1) {
        pz0 += __shfl_down(pz0, off);
        pz1 += __shfl_down(pz1, off);
    }
    if (lane == 0) {
        float2* zp = (float2*)(z + (size_t)si * 2);
        *zp = make_float2(pz0 * di, pz1 * di);  // prescale for layer-2 aggregation
    }
}

// Layer-2 aggregation over prescaled z'. 16 lanes per node (avg degree 16):
// 4 nodes/wave, width-16 shuffle reduce. out[i] = (Σ z'[s] + z'[i])*dinv[i] + b2.
__launch_bounds__(256)
__global__ void agg2_k(const float* __restrict__ z, const unsigned* __restrict__ rp,
                       const unsigned* __restrict__ col, const float* __restrict__ dinv,
                       const float* __restrict__ b2, float* __restrict__ out) {
    int i = (blockIdx.x * 256 + threadIdx.x) >> 4;
    int sl = threadIdx.x & 15;
    if (i >= NN) return;

    unsigned p0 = rp[i], p1 = rp[i + 1];
    float a0 = 0.f, a1 = 0.f;
    for (unsigned e = p0 + sl; e < p1; e += 16) {
        unsigned s = col[e];
        float2 v = ((const float2*)z)[s];
        a0 += v.x;
        a1 += v.y;
    }
#pragma unroll
    for (int off = 8; off > 0; off >>= 1) {
        a0 += __shfl_down(a0, off, 16);
        a1 += __shfl_down(a1, off, 16);
    }
    if (sl == 0) {
        float di = dinv[i];
        float2 zi = ((const float2*)z)[i];
        out[(size_t)i * 2]     = (a0 + zi.x) * di + b2[0];
        out[(size_t)i * 2 + 1] = (a1 + zi.y) * di + b2[1];
    }
}

extern "C" void kernel_launch(void* const* d_in, const int* in_sizes, int n_in,
                              void* d_out, int out_size, void* d_ws, size_t ws_size,
                              hipStream_t stream) {
    const float* x  = (const float*)d_in[0];
    const int*   ei = (const int*)d_in[1];
    const float* W1 = (const float*)d_in[2];
    const float* b1 = (const float*)d_in[3];
    const float* W2 = (const float*)d_in[4];
    const float* b2 = (const float*)d_in[5];
    float* out = (float*)d_out;

    char* ws = (char*)d_ws;
    unsigned* part = (unsigned*)(ws);               // overlaps h, dead before gemm1
    unsigned* offs = (unsigned*)(ws + 6400000);     // overlaps h
    unsigned* base = (unsigned*)(ws + 7100000);     // overlaps h
    _Float16* h    = (_Float16*)(ws);
    float*    z    = (float*)(ws + 25600000);
    float*    dinv = (float*)(ws + 26400000);
    unsigned* rp   = (unsigned*)(ws + 26800000);
    unsigned* col  = (unsigned*)(ws + 27200016);
    _Float16* Wt   = (_Float16*)(ws + 33600016);

    p1_count_k<<<NBLK_P, 256, 0, stream>>>(ei, offs, W1, Wt);
    p2a_k<<<NBK, 256, 0, stream>>>(offs, base);
    p2b_k<<<1, 1024, 0, stream>>>(base);
    p3_scatter_k<<<NBLK_P, 256, 0, stream>>>(ei, offs, base, part);
    p4_csr_k<<<NBK, 256, 0, stream>>>(part, base, rp, dinv, col);

    gemm1_k<<<(NN + 127) / 128, 256, 0, stream>>>(x, Wt, dinv, h);
    agg1_k<<<(NN + 3) / 4, 256, 0, stream>>>(h, rp, col, dinv, b1, W2, z);
    agg2_k<<<(NN * 16 + 255) / 256, 256, 0, stream>>>(z, rp, col, dinv, b2, out);
}